// Round 1
// baseline (821.719 us; speedup 1.0000x reference)
//
#include <hip/hip_runtime.h>

// ScaledDotProductAttention: B=2,H=16,S=2048,DK=DV=64, fp32 in/out, bool mask (True => -1e9).
// Flash-attention, bf16 MFMA (16x16x32), online softmax in registers (base-2 units).

#define LOG2E 1.4426950408889634f
#define QSCALE (0.125f * LOG2E)          // fold 1/sqrt(64) and log2(e) into Q
#define MASKVAL (-1.0e9f * LOG2E)        // masked score in base-2 units

typedef __attribute__((ext_vector_type(8))) short short8;   // 8 x bf16 (4 VGPRs)
typedef __attribute__((ext_vector_type(4))) float f32x4;    // MFMA acc

__device__ __forceinline__ short bf16rne(float x) {
  union { float f; unsigned u; } cv; cv.f = x;
  unsigned u = cv.u;
  u += 0x7fffu + ((u >> 16) & 1u);       // round-to-nearest-even
  return (short)(u >> 16);
}

// Mask format autodetect: 0 = int32 (0/1), 1 = uint8 (0/1), 2 = float32 (0.0/1.0)
__global__ void detect_mask_fmt(const unsigned* __restrict__ m, int* __restrict__ flag) {
  unsigned v = m[threadIdx.x];
  unsigned long long isf = __ballot(v == 0x3F800000u);
  unsigned long long big = __ballot(v > 1u);
  if (threadIdx.x == 0) *flag = (isf != 0ull) ? 2 : ((big != 0ull) ? 1 : 0);
}

__launch_bounds__(256)
__global__ void attn_fwd(const float* __restrict__ qp, const float* __restrict__ kp,
                         const float* __restrict__ vp, const void* __restrict__ mp,
                         float* __restrict__ op, const int* __restrict__ fmtp) {
  constexpr int S = 2048, D = 64;
  const int fmt  = *fmtp;
  const int tid  = threadIdx.x;
  const int lane = tid & 63;
  const int w    = tid >> 6;          // wave 0..3 (16 q-rows each)
  const int c    = lane & 15;         // MFMA n / m index
  const int quad = lane >> 4;         // MFMA k-chunk / row-group

  const int bh = blockIdx.x >> 5;     // 0..31
  const int q0 = (blockIdx.x & 31) * 64;

  // +8 bf16 pad => row stride 144B: 16B-aligned, bank-uniform for b128 frag reads
  __shared__ short ks[64][72];        // K tile, [key][dim]
  __shared__ short vst[64][72];       // V tile transposed, [dim][key]
  __shared__ short psld[4][16][72];   // per-wave P tile, [m][k]

  // ---- Q A-fragments (rows q0 + w*16 + c), kept in registers for all iters ----
  const float* qg = qp + ((size_t)(bh * S + q0 + w * 16 + c)) * D;
  short8 qA[2];
#pragma unroll
  for (int kk = 0; kk < 2; ++kk) {
    const float* p = qg + kk * 32 + quad * 8;
    float4 x = *(const float4*)(p);
    float4 y = *(const float4*)(p + 4);
    short8 f;
    f[0] = bf16rne(x.x * QSCALE); f[1] = bf16rne(x.y * QSCALE);
    f[2] = bf16rne(x.z * QSCALE); f[3] = bf16rne(x.w * QSCALE);
    f[4] = bf16rne(y.x * QSCALE); f[5] = bf16rne(y.y * QSCALE);
    f[6] = bf16rne(y.z * QSCALE); f[7] = bf16rne(y.w * QSCALE);
    qA[kk] = f;
  }

  f32x4 O[4];
#pragma unroll
  for (int t = 0; t < 4; ++t) O[t] = (f32x4){0.f, 0.f, 0.f, 0.f};
  float M[4], L[4];
#pragma unroll
  for (int r = 0; r < 4; ++r) { M[r] = -3.0e38f; L[r] = 0.f; }

  const int skey = tid >> 2;          // K staging: key 0..63
  const int sdb  = (tid & 3) * 16;    // K staging: dim base

  for (int it = 0; it < 32; ++it) {
    const int k0 = it * 64;
    __syncthreads();                  // prev-iter frag reads done before overwrite

    // ---- stage K tile (coalesced rows -> bf16 LDS) ----
    {
      const float* g = kp + ((size_t)(bh * S + k0 + skey)) * D + sdb;
      float4 a = *(const float4*)(g);
      float4 b = *(const float4*)(g + 4);
      float4 e = *(const float4*)(g + 8);
      float4 d = *(const float4*)(g + 12);
      short8 s0, s1;
      s0[0] = bf16rne(a.x); s0[1] = bf16rne(a.y); s0[2] = bf16rne(a.z); s0[3] = bf16rne(a.w);
      s0[4] = bf16rne(b.x); s0[5] = bf16rne(b.y); s0[6] = bf16rne(b.z); s0[7] = bf16rne(b.w);
      s1[0] = bf16rne(e.x); s1[1] = bf16rne(e.y); s1[2] = bf16rne(e.z); s1[3] = bf16rne(e.w);
      s1[4] = bf16rne(d.x); s1[5] = bf16rne(d.y); s1[6] = bf16rne(d.z); s1[7] = bf16rne(d.w);
      *(short8*)&ks[skey][sdb]     = s0;
      *(short8*)&ks[skey][sdb + 8] = s1;
    }
    // ---- stage V tile transposed (gather columns, contiguous LDS writes) ----
#pragma unroll
    for (int h = 0; h < 2; ++h) {
      int cid = tid + h * 256;
      int dim = cid >> 3;
      int kc  = cid & 7;
      const float* g = vp + ((size_t)(bh * S + k0 + kc * 8)) * D + dim;
      short8 s;
#pragma unroll
      for (int j = 0; j < 8; ++j) s[j] = bf16rne(g[(size_t)j * D]);
      *(short8*)&vst[dim][kc * 8] = s;
    }
    __syncthreads();

    // ---- QK^T: 4 n-tiles x 2 k-steps ----
    f32x4 Sc[4];
#pragma unroll
    for (int t = 0; t < 4; ++t) {
      short8 b0 = *(const short8*)&ks[t * 16 + c][quad * 8];
      short8 b1 = *(const short8*)&ks[t * 16 + c][32 + quad * 8];
      f32x4 z = (f32x4){0.f, 0.f, 0.f, 0.f};
      z = __builtin_amdgcn_mfma_f32_16x16x32_bf16(qA[0], b0, z, 0, 0, 0);
      z = __builtin_amdgcn_mfma_f32_16x16x32_bf16(qA[1], b1, z, 0, 0, 0);
      Sc[t] = z;
    }

    float tv[4][4];                   // [t][reg] ; row = quad*4+reg, col = t*16+c
#pragma unroll
    for (int t = 0; t < 4; ++t)
#pragma unroll
      for (int r = 0; r < 4; ++r) tv[t][r] = Sc[t][r];

    // ---- mask (True => MASKVAL) ----
    const long long m0 = ((long long)bh * S + (q0 + w * 16 + quad * 4)) * S + k0 + c;
    if (fmt == 1) {
      const unsigned char* mb = (const unsigned char*)mp + m0;
#pragma unroll
      for (int r = 0; r < 4; ++r)
#pragma unroll
        for (int t = 0; t < 4; ++t)
          if (mb[(long long)r * S + t * 16]) tv[t][r] = MASKVAL;
    } else if (fmt == 0) {
      const int* mi = (const int*)mp + m0;
#pragma unroll
      for (int r = 0; r < 4; ++r)
#pragma unroll
        for (int t = 0; t < 4; ++t)
          if (mi[(long long)r * S + t * 16] != 0) tv[t][r] = MASKVAL;
    } else {
      const float* mf = (const float*)mp + m0;
#pragma unroll
      for (int r = 0; r < 4; ++r)
#pragma unroll
        for (int t = 0; t < 4; ++t)
          if (mf[(long long)r * S + t * 16] != 0.f) tv[t][r] = MASKVAL;
    }

    // ---- online softmax (base-2), rows 4*quad+r, reduce over 16 lanes of quad ----
    float pm[4];
#pragma unroll
    for (int r = 0; r < 4; ++r)
      pm[r] = fmaxf(fmaxf(tv[0][r], tv[1][r]), fmaxf(tv[2][r], tv[3][r]));
#pragma unroll
    for (int xm = 1; xm < 16; xm <<= 1)
#pragma unroll
      for (int r = 0; r < 4; ++r) pm[r] = fmaxf(pm[r], __shfl_xor(pm[r], xm));

    float al[4];
#pragma unroll
    for (int r = 0; r < 4; ++r) {
      float Mn = fmaxf(M[r], pm[r]);
      al[r] = exp2f(M[r] - Mn);
      M[r] = Mn;
    }
#pragma unroll
    for (int t = 0; t < 4; ++t)
#pragma unroll
      for (int r = 0; r < 4; ++r) tv[t][r] = exp2f(tv[t][r] - M[r]);

    float rs[4];
#pragma unroll
    for (int r = 0; r < 4; ++r)
      rs[r] = (tv[0][r] + tv[1][r]) + (tv[2][r] + tv[3][r]);
#pragma unroll
    for (int xm = 1; xm < 16; xm <<= 1)
#pragma unroll
      for (int r = 0; r < 4; ++r) rs[r] += __shfl_xor(rs[r], xm);

    f32x4 alv = (f32x4){al[0], al[1], al[2], al[3]};
#pragma unroll
    for (int r = 0; r < 4; ++r) L[r] = L[r] * al[r] + rs[r];
#pragma unroll
    for (int t = 0; t < 4; ++t) O[t] *= alv;

    // ---- P -> LDS (C-layout scatter) then re-read as A-operand ----
#pragma unroll
    for (int r = 0; r < 4; ++r)
#pragma unroll
      for (int t = 0; t < 4; ++t)
        psld[w][quad * 4 + r][t * 16 + c] = bf16rne(tv[t][r]);
    __syncthreads();

    short8 pA0 = *(const short8*)&psld[w][c][quad * 8];
    short8 pA1 = *(const short8*)&psld[w][c][32 + quad * 8];
#pragma unroll
    for (int t = 0; t < 4; ++t) {
      short8 v0 = *(const short8*)&vst[t * 16 + c][quad * 8];
      short8 v1 = *(const short8*)&vst[t * 16 + c][32 + quad * 8];
      O[t] = __builtin_amdgcn_mfma_f32_16x16x32_bf16(pA0, v0, O[t], 0, 0, 0);
      O[t] = __builtin_amdgcn_mfma_f32_16x16x32_bf16(pA1, v1, O[t], 0, 0, 0);
    }
  }

  // ---- epilogue: O / L ----
#pragma unroll
  for (int r = 0; r < 4; ++r) {
    float inv = 1.f / L[r];
    const size_t ob = ((size_t)(bh * S + q0 + w * 16 + quad * 4 + r)) * D;
#pragma unroll
    for (int t = 0; t < 4; ++t) op[ob + t * 16 + c] = O[t][r] * inv;
  }
}

extern "C" void kernel_launch(void* const* d_in, const int* in_sizes, int n_in,
                              void* d_out, int out_size, void* d_ws, size_t ws_size,
                              hipStream_t stream) {
  const float* q = (const float*)d_in[0];
  const float* k = (const float*)d_in[1];
  const float* v = (const float*)d_in[2];
  const void*  m = d_in[3];
  int* flag = (int*)d_ws;
  detect_mask_fmt<<<1, 64, 0, stream>>>((const unsigned*)m, flag);
  attn_fwd<<<1024, 256, 0, stream>>>(q, k, v, m, (float*)d_out, flag);
}